// Round 1
// baseline (418.264 us; speedup 1.0000x reference)
//
#include <hip/hip_runtime.h>
#include <hip/hip_bf16.h>
#include <cstdint>

typedef __attribute__((ext_vector_type(4))) float f32x4;
typedef _Float16 f16x8 __attribute__((ext_vector_type(8)));

#define BN_EPS 1e-5f

// ---------------- fp32 -> fp16 cast (vectorized, 8 elems/thread) ----------------
__global__ __launch_bounds__(256)
void cast_f32_f16(const float* __restrict__ src, _Float16* __restrict__ dst, int n8) {
    int i = blockIdx.x * blockDim.x + threadIdx.x;
    if (i >= n8) return;
    const float4* s4 = (const float4*)src;
    float4 a = s4[2 * (size_t)i];
    float4 b = s4[2 * (size_t)i + 1];
    f16x8 h;
    h[0] = (_Float16)a.x; h[1] = (_Float16)a.y; h[2] = (_Float16)a.z; h[3] = (_Float16)a.w;
    h[4] = (_Float16)b.x; h[5] = (_Float16)b.y; h[6] = (_Float16)b.z; h[7] = (_Float16)b.w;
    *(f16x8*)(dst + 8 * (size_t)i) = h;
}

// async global->LDS, 16B per lane, wave-uniform LDS base
__device__ __forceinline__ void async16(const _Float16* g, _Float16* l) {
    __builtin_amdgcn_global_load_lds(
        (const __attribute__((address_space(1))) unsigned int*)(uintptr_t)g,
        (__attribute__((address_space(3))) unsigned int*)(uintptr_t)l,
        16, 0, 0);
}

// ---------------- GEMM (A[M][K] f16, B[N][K] f16 = W, i.e. B^T layout) ----------------
// + fused Ghost BatchNorm (BM=128 == VBS) + priors multiply. Writes z = gbn(A@W^T)*priors.
__global__ __launch_bounds__(256)
void gemm_gbn_kernel(const _Float16* __restrict__ A,
                     const _Float16* __restrict__ Bw,
                     const float* __restrict__ priors,
                     const float* __restrict__ gamma,
                     const float* __restrict__ beta,
                     float* __restrict__ Z,
                     int M, int N, int K)
{
    __shared__ _Float16 As[128 * 32];
    __shared__ _Float16 Bs[128 * 32];
    __shared__ float red[2][128][2];   // [waveRow][col][{sum, sumsq}]

    const int tid  = threadIdx.x;
    const int lane = tid & 63;
    const int wid  = tid >> 6;   // 0..3
    const int wr   = wid >> 1;   // wave row 0/1 (64 rows each)
    const int wc   = wid & 1;    // wave col 0/1 (64 cols each)
    const int fr   = lane & 15;  // fragment row/col
    const int kg   = lane >> 4;  // k-group (8 elems each)

    const int row0 = blockIdx.x * 128;   // == ghost-batch index * VBS
    const int col0 = blockIdx.y * 128;

    // staging: thread t covers tile row t/4 (+64 on 2nd issue), col (t%4)*8
    const int srow = tid >> 2;
    const int scol = (tid & 3) * 8;
    const _Float16* aSrc = A  + (size_t)(row0 + srow) * K + scol;
    const _Float16* bSrc = Bw + (size_t)(col0 + srow) * K + scol;

    // wave-uniform LDS bases: wave w writes bytes [w*1024, w*1024+1024) per issue-half
    _Float16* aDst0 = As + wid * 512;
    _Float16* aDst1 = As + 2048 + wid * 512;
    _Float16* bDst0 = Bs + wid * 512;
    _Float16* bDst1 = Bs + 2048 + wid * 512;

    f32x4 acc[4][4];
    #pragma unroll
    for (int m = 0; m < 4; ++m)
        #pragma unroll
        for (int n = 0; n < 4; ++n)
            acc[m][n] = (f32x4)0.0f;

    for (int k0 = 0; k0 < K; k0 += 32) {
        __syncthreads();                    // previous tile fully consumed
        async16(aSrc + k0,                 aDst0);
        async16(aSrc + (size_t)64 * K + k0, aDst1);
        async16(bSrc + k0,                 bDst0);
        async16(bSrc + (size_t)64 * K + k0, bDst1);
        __syncthreads();                    // drains vmcnt -> tile visible

        f16x8 af[4], bf[4];
        #pragma unroll
        for (int m = 0; m < 4; ++m)
            af[m] = *(const f16x8*)(As + (wr * 64 + m * 16 + fr) * 32 + kg * 8);
        #pragma unroll
        for (int n = 0; n < 4; ++n)
            bf[n] = *(const f16x8*)(Bs + (wc * 64 + n * 16 + fr) * 32 + kg * 8);

        #pragma unroll
        for (int m = 0; m < 4; ++m)
            #pragma unroll
            for (int n = 0; n < 4; ++n)
                acc[m][n] = __builtin_amdgcn_mfma_f32_16x16x32_f16(af[m], bf[n], acc[m][n], 0, 0, 0);
    }

    // ---- fused Ghost BatchNorm epilogue ----
    // per-column (over the 128 rows of this block == one virtual batch) sum & sumsq
    #pragma unroll
    for (int n = 0; n < 4; ++n) {
        float s1 = 0.f, s2 = 0.f;
        #pragma unroll
        for (int m = 0; m < 4; ++m)
            #pragma unroll
            for (int j = 0; j < 4; ++j) {
                float v = acc[m][n][j];
                s1 += v; s2 += v * v;
            }
        // combine the 4 lane-groups (rows kg*4..kg*4+3 within each fragment)
        s1 += __shfl_xor(s1, 16); s2 += __shfl_xor(s2, 16);
        s1 += __shfl_xor(s1, 32); s2 += __shfl_xor(s2, 32);
        if (lane < 16) {
            red[wr][wc * 64 + n * 16 + lane][0] = s1;
            red[wr][wc * 64 + n * 16 + lane][1] = s2;
        }
    }
    __syncthreads();

    const int rowb = row0 + wr * 64 + kg * 4;
    #pragma unroll
    for (int n = 0; n < 4; ++n) {
        const int c = wc * 64 + n * 16 + fr;
        float s1 = red[0][c][0] + red[1][c][0];
        float s2 = red[0][c][1] + red[1][c][1];
        float mean = s1 * (1.f / 128.f);
        float var  = s2 * (1.f / 128.f) - mean * mean;
        float rstd = rsqrtf(var + BN_EPS);
        float g = gamma[col0 + c] * rstd;
        float b = beta[col0 + c] - mean * g;     // xn*gamma+beta == acc*g + b
        #pragma unroll
        for (int m = 0; m < 4; ++m) {
            #pragma unroll
            for (int j = 0; j < 4; ++j) {
                int r = rowb + m * 16 + j;
                size_t off = (size_t)r * N + col0 + c;
                Z[off] = (acc[m][n][j] * g + b) * priors[off];
            }
        }
    }
}

// ---------------- sparsemax: one wave per row of 1024, exact Michelot projection ----------------
__device__ __forceinline__ float waveSum(float v) {
    #pragma unroll
    for (int off = 32; off > 0; off >>= 1) v += __shfl_xor(v, off);
    return v;
}

__global__ __launch_bounds__(256)
void sparsemax_kernel(float* __restrict__ Z) {
    const int lane = threadIdx.x & 63;
    const int wid  = threadIdx.x >> 6;
    const size_t row = (size_t)blockIdx.x * 4 + wid;
    float4* zr4 = (float4*)(Z + row * 1024);

    float p[16];
    #pragma unroll
    for (int j = 0; j < 4; ++j) {
        float4 t = zr4[lane * 4 + j];
        p[4 * j + 0] = t.x; p[4 * j + 1] = t.y; p[4 * j + 2] = t.z; p[4 * j + 3] = t.w;
    }

    float s = 0.f;
    #pragma unroll
    for (int i = 0; i < 16; ++i) s += p[i];
    s = waveSum(s);

    float kc  = 1024.f;
    float tau = (s - 1.f) * (1.f / 1024.f);
    for (int it = 0; it < 64; ++it) {
        float s2 = 0.f, c2 = 0.f;
        #pragma unroll
        for (int i = 0; i < 16; ++i) {
            if (p[i] > tau) { s2 += p[i]; c2 += 1.f; }
        }
        s2 = waveSum(s2); c2 = waveSum(c2);
        if (c2 == kc) break;        // support stable -> tau is exact
        kc = c2;
        tau = (s2 - 1.f) / c2;
    }

    #pragma unroll
    for (int j = 0; j < 4; ++j) {
        float4 o;
        o.x = fmaxf(p[4 * j + 0] - tau, 0.f);
        o.y = fmaxf(p[4 * j + 1] - tau, 0.f);
        o.z = fmaxf(p[4 * j + 2] - tau, 0.f);
        o.w = fmaxf(p[4 * j + 3] - tau, 0.f);
        zr4[lane * 4 + j] = o;
    }
}

extern "C" void kernel_launch(void* const* d_in, const int* in_sizes, int n_in,
                              void* d_out, int out_size, void* d_ws, size_t ws_size,
                              hipStream_t stream)
{
    const float* priors = (const float*)d_in[0];
    const float* feat   = (const float*)d_in[1];
    const float* W      = (const float*)d_in[2];
    const float* gamma  = (const float*)d_in[3];
    const float* beta   = (const float*)d_in[4];
    float* out = (float*)d_out;

    const int Nf = in_sizes[3];              // 1024
    const int Kf = in_sizes[2] / Nf;         // 2048
    const int Mr = in_sizes[1] / Kf;         // 32768

    _Float16* Ah = (_Float16*)d_ws;                                  // M*K*2 = 128 MB
    _Float16* Wh = (_Float16*)((char*)d_ws + (size_t)Mr * Kf * 2);   // N*K*2 =   4 MB

    {
        int n8 = Mr * (Kf / 8);
        cast_f32_f16<<<(n8 + 255) / 256, 256, 0, stream>>>(feat, Ah, n8);
    }
    {
        int n8 = Nf * (Kf / 8);
        cast_f32_f16<<<(n8 + 255) / 256, 256, 0, stream>>>(W, Wh, n8);
    }

    dim3 grid(Mr / 128, Nf / 128);
    gemm_gbn_kernel<<<grid, 256, 0, stream>>>(Ah, Wh, priors, gamma, beta, out, Mr, Nf, Kf);

    sparsemax_kernel<<<Mr / 4, 256, 0, stream>>>(out);
}

// Round 2
// 343.083 us; speedup vs baseline: 1.2191x; 1.2191x over previous
//
#include <hip/hip_runtime.h>
#include <hip/hip_bf16.h>
#include <cstdint>

typedef __attribute__((ext_vector_type(4))) float f32x4;
typedef _Float16 f16x8 __attribute__((ext_vector_type(8)));

#define BN_EPS 1e-5f

// ---------------- fp32 -> fp16 cast (vectorized, 8 elems/thread) ----------------
__global__ __launch_bounds__(256)
void cast_f32_f16(const float* __restrict__ src, _Float16* __restrict__ dst, int n8) {
    int i = blockIdx.x * blockDim.x + threadIdx.x;
    if (i >= n8) return;
    const float4* s4 = (const float4*)src;
    float4 a = s4[2 * (size_t)i];
    float4 b = s4[2 * (size_t)i + 1];
    f16x8 h;
    h[0] = (_Float16)a.x; h[1] = (_Float16)a.y; h[2] = (_Float16)a.z; h[3] = (_Float16)a.w;
    h[4] = (_Float16)b.x; h[5] = (_Float16)b.y; h[6] = (_Float16)b.z; h[7] = (_Float16)b.w;
    *(f16x8*)(dst + 8 * (size_t)i) = h;
}

// async global->LDS, 16B per lane, wave-uniform LDS base
__device__ __forceinline__ void async16(const char* g, _Float16* l) {
    __builtin_amdgcn_global_load_lds(
        (const __attribute__((address_space(1))) unsigned int*)(uintptr_t)g,
        (__attribute__((address_space(3))) unsigned int*)(uintptr_t)l,
        16, 0, 0);
}

// ================= 256x256 tile, BK=32, 4-buffer deep-pipelined GEMM =================
// A[M][K] f16, B=W[N][K] f16. Fused Ghost BN (128-row virtual batch == wr-half) + priors.
// LDS per buffer: A 256x32 f16 (16KB) + B 256x32 f16 (16KB); 4 buffers = 128KB.
// Pipeline: while computing K-tile kt (2 phases), stage kt+3. vmcnt(8) once per K-tile.

template<int WAITN, bool STAGE>
__device__ __forceinline__ void ktile(
    int kt, _Float16* As, _Float16* Bs,
    const char* a0, const char* a1, const char* b0, const char* b1,
    int wid, int aoff, int boff, f16x8 (&b)[4], f32x4 (&acc)[8][4])
{
    const char* ab = (const char*)As + ((kt & 3) << 14);
    const char* bb = (const char*)Bs + ((kt & 3) << 14);
    f16x8 a[4];

    // ---------- phase 0: quadrant m0-3 x n0-3 ----------
    #pragma unroll
    for (int m = 0; m < 4; ++m) a[m] = *(const f16x8*)(ab + aoff + m * 1024);
    #pragma unroll
    for (int n = 0; n < 4; ++n) b[n] = *(const f16x8*)(bb + boff + n * 1024);
    if (STAGE) {
        _Float16* d = As + ((kt + 3) & 3) * 8192 + wid * 512;
        async16(a0 + (size_t)(kt + 3) * 64, d);
        async16(a1 + (size_t)(kt + 3) * 64, d + 4096);
    }
    __builtin_amdgcn_s_barrier();
    asm volatile("s_waitcnt lgkmcnt(0)" ::: "memory");
    __builtin_amdgcn_sched_barrier(0);
    __builtin_amdgcn_s_setprio(1);
    #pragma unroll
    for (int m = 0; m < 4; ++m)
        #pragma unroll
        for (int n = 0; n < 4; ++n)
            acc[m][n] = __builtin_amdgcn_mfma_f32_16x16x32_f16(a[m], b[n], acc[m][n], 0, 0, 0);
    __builtin_amdgcn_s_setprio(0);
    __builtin_amdgcn_s_barrier();

    // ---------- phase 1: quadrant m4-7 x n0-3 (b[] reused) ----------
    #pragma unroll
    for (int m = 0; m < 4; ++m) a[m] = *(const f16x8*)(ab + aoff + (4 + m) * 1024);
    if (STAGE) {
        _Float16* d = Bs + ((kt + 3) & 3) * 8192 + wid * 512;
        async16(b0 + (size_t)(kt + 3) * 64, d);
        async16(b1 + (size_t)(kt + 3) * 64, d + 4096);
    }
    __builtin_amdgcn_s_barrier();
    asm volatile("s_waitcnt lgkmcnt(0)" ::: "memory");
    __builtin_amdgcn_sched_barrier(0);
    __builtin_amdgcn_s_setprio(1);
    #pragma unroll
    for (int m = 0; m < 4; ++m)
        #pragma unroll
        for (int n = 0; n < 4; ++n)
            acc[4 + m][n] = __builtin_amdgcn_mfma_f32_16x16x32_f16(a[m], b[n], acc[4 + m][n], 0, 0, 0);
    __builtin_amdgcn_s_setprio(0);
    if (WAITN == 8)      { asm volatile("s_waitcnt vmcnt(8)" ::: "memory"); }
    else if (WAITN == 4) { asm volatile("s_waitcnt vmcnt(4)" ::: "memory"); }
    else                 { asm volatile("s_waitcnt vmcnt(0)" ::: "memory"); }
    __builtin_amdgcn_sched_barrier(0);
    __builtin_amdgcn_s_barrier();
}

__global__ __launch_bounds__(512, 2)
void gemm_gbn_kernel(const _Float16* __restrict__ A,
                     const _Float16* __restrict__ Bw,
                     const float* __restrict__ priors,
                     const float* __restrict__ gamma,
                     const float* __restrict__ beta,
                     float* __restrict__ Z,
                     int M, int N, int K)
{
    __shared__ __align__(16) _Float16 As[4 * 8192];   // 64 KB
    __shared__ __align__(16) _Float16 Bs[4 * 8192];   // 64 KB

    const int tid  = threadIdx.x;
    const int lane = tid & 63;
    const int wid  = tid >> 6;     // 0..7
    const int wr   = wid >> 2;     // 0..1  (128-row half == one virtual batch)
    const int wc   = wid & 3;      // 0..3  (64-col slice)
    const int fr   = lane & 15;
    const int kg   = lane >> 4;

    // XCD-aware bijective swizzle (nwg = 512, divisible by 8)
    const int bid = blockIdx.x;
    const int swz = (bid & 7) * 64 + (bid >> 3);
    const int row0 = (swz >> 2) * 256;
    const int col0 = (swz & 3) * 256;

    // staging sources: thread t covers tile row t/4 (+128 for second issue), k-bytes (t&3)*16
    const char* a0 = (const char*)A  + (size_t)(row0 + (tid >> 2)) * (size_t)K * 2 + (tid & 3) * 16;
    const char* a1 = a0 + (size_t)128 * K * 2;
    const char* b0 = (const char*)Bw + (size_t)(col0 + (tid >> 2)) * (size_t)K * 2 + (tid & 3) * 16;
    const char* b1 = b0 + (size_t)128 * K * 2;

    // LDS fragment byte offsets (linear [256][32] f16 layout, 64B rows)
    const int aoff = (wr * 128 + fr) * 64 + kg * 16;
    const int boff = (wc * 64 + fr) * 64 + kg * 16;

    f32x4 acc[8][4];
    #pragma unroll
    for (int m = 0; m < 8; ++m)
        #pragma unroll
        for (int n = 0; n < 4; ++n)
            acc[m][n] = (f32x4)0.0f;
    f16x8 bfrag[4];

    // prologue: stage K-tiles 0,1,2 (A then B each) -> buffers 0,1,2
    #pragma unroll
    for (int t = 0; t < 3; ++t) {
        _Float16* dA = As + t * 8192 + wid * 512;
        async16(a0 + (size_t)t * 64, dA);
        async16(a1 + (size_t)t * 64, dA + 4096);
        _Float16* dB = Bs + t * 8192 + wid * 512;
        async16(b0 + (size_t)t * 64, dB);
        async16(b1 + (size_t)t * 64, dB + 4096);
    }
    asm volatile("s_waitcnt vmcnt(8)" ::: "memory");   // tile 0 resident; tiles 1,2 in flight
    __builtin_amdgcn_sched_barrier(0);
    __builtin_amdgcn_s_barrier();

    const int nt = K >> 5;                 // 64 K-tiles
    for (int kt = 0; kt < nt - 3; ++kt)    // stages kt+3 (up to nt-1), waits vmcnt(8)
        ktile<8, true>(kt, As, Bs, a0, a1, b0, b1, wid, aoff, boff, bfrag, acc);
    ktile<4, false>(nt - 3, As, Bs, a0, a1, b0, b1, wid, aoff, boff, bfrag, acc);
    ktile<0, false>(nt - 2, As, Bs, a0, a1, b0, b1, wid, aoff, boff, bfrag, acc);
    ktile<0, false>(nt - 1, As, Bs, a0, a1, b0, b1, wid, aoff, boff, bfrag, acc);

    // ---- fused Ghost BatchNorm + priors epilogue (wave-local: wr half = one VBS) ----
    #pragma unroll
    for (int n = 0; n < 4; ++n) {
        float s1 = 0.f, s2 = 0.f;
        #pragma unroll
        for (int m = 0; m < 8; ++m)
            #pragma unroll
            for (int j = 0; j < 4; ++j) {
                float v = acc[m][n][j];
                s1 += v; s2 += v * v;
            }
        s1 += __shfl_xor(s1, 16); s2 += __shfl_xor(s2, 16);
        s1 += __shfl_xor(s1, 32); s2 += __shfl_xor(s2, 32);
        float mean = s1 * (1.f / 128.f);
        float var  = s2 * (1.f / 128.f) - mean * mean;
        float rstd = rsqrtf(var + BN_EPS);
        const int c = col0 + wc * 64 + n * 16 + fr;
        float g = gamma[c] * rstd;
        float b = beta[c] - mean * g;
        #pragma unroll
        for (int m = 0; m < 8; ++m)
            #pragma unroll
            for (int j = 0; j < 4; ++j) {
                int r = row0 + wr * 128 + m * 16 + kg * 4 + j;
                size_t off = (size_t)r * N + c;
                Z[off] = (acc[m][n][j] * g + b) * priors[off];
            }
    }
}

// ---------------- sparsemax: one wave per row of 1024, exact Michelot projection ----------------
__device__ __forceinline__ float waveSum(float v) {
    #pragma unroll
    for (int off = 32; off > 0; off >>= 1) v += __shfl_xor(v, off);
    return v;
}

__global__ __launch_bounds__(256)
void sparsemax_kernel(float* __restrict__ Z) {
    const int lane = threadIdx.x & 63;
    const int wid  = threadIdx.x >> 6;
    const size_t row = (size_t)blockIdx.x * 4 + wid;
    float4* zr4 = (float4*)(Z + row * 1024);

    float p[16];
    #pragma unroll
    for (int j = 0; j < 4; ++j) {
        float4 t = zr4[lane * 4 + j];
        p[4 * j + 0] = t.x; p[4 * j + 1] = t.y; p[4 * j + 2] = t.z; p[4 * j + 3] = t.w;
    }

    float s = 0.f;
    #pragma unroll
    for (int i = 0; i < 16; ++i) s += p[i];
    s = waveSum(s);

    float kc  = 1024.f;
    float tau = (s - 1.f) * (1.f / 1024.f);
    for (int it = 0; it < 64; ++it) {
        float s2 = 0.f, c2 = 0.f;
        #pragma unroll
        for (int i = 0; i < 16; ++i) {
            if (p[i] > tau) { s2 += p[i]; c2 += 1.f; }
        }
        s2 = waveSum(s2); c2 = waveSum(c2);
        if (c2 == kc) break;        // support stable -> tau exact
        kc = c2;
        tau = (s2 - 1.f) / c2;
    }

    #pragma unroll
    for (int j = 0; j < 4; ++j) {
        float4 o;
        o.x = fmaxf(p[4 * j + 0] - tau, 0.f);
        o.y = fmaxf(p[4 * j + 1] - tau, 0.f);
        o.z = fmaxf(p[4 * j + 2] - tau, 0.f);
        o.w = fmaxf(p[4 * j + 3] - tau, 0.f);
        zr4[lane * 4 + j] = o;
    }
}

extern "C" void kernel_launch(void* const* d_in, const int* in_sizes, int n_in,
                              void* d_out, int out_size, void* d_ws, size_t ws_size,
                              hipStream_t stream)
{
    const float* priors = (const float*)d_in[0];
    const float* feat   = (const float*)d_in[1];
    const float* W      = (const float*)d_in[2];
    const float* gamma  = (const float*)d_in[3];
    const float* beta   = (const float*)d_in[4];
    float* out = (float*)d_out;

    const int Nf = in_sizes[3];              // 1024
    const int Kf = in_sizes[2] / Nf;         // 2048
    const int Mr = in_sizes[1] / Kf;         // 32768

    _Float16* Ah = (_Float16*)d_ws;                                  // M*K*2 = 128 MB
    _Float16* Wh = (_Float16*)((char*)d_ws + (size_t)Mr * Kf * 2);   // N*K*2 =   4 MB

    {
        int n8 = Mr * (Kf / 8);
        cast_f32_f16<<<(n8 + 255) / 256, 256, 0, stream>>>(feat, Ah, n8);
    }
    {
        int n8 = Nf * (Kf / 8);
        cast_f32_f16<<<(n8 + 255) / 256, 256, 0, stream>>>(W, Wh, n8);
    }

    int nblk = (Mr / 256) * (Nf / 256);      // 512, divisible by 8
    gemm_gbn_kernel<<<nblk, 512, 0, stream>>>(Ah, Wh, priors, gamma, beta, out, Mr, Nf, Kf);

    sparsemax_kernel<<<Mr / 4, 256, 0, stream>>>(out);
}

// Round 3
// 337.555 us; speedup vs baseline: 1.2391x; 1.0164x over previous
//
#include <hip/hip_runtime.h>
#include <hip/hip_bf16.h>
#include <cstdint>

typedef __attribute__((ext_vector_type(4))) float f32x4;
typedef _Float16 f16x8 __attribute__((ext_vector_type(8)));

#define BN_EPS 1e-5f

// ---------------- fp32 -> fp16 cast (vectorized, 8 elems/thread) ----------------
__global__ __launch_bounds__(256)
void cast_f32_f16(const float* __restrict__ src, _Float16* __restrict__ dst, int n8) {
    int i = blockIdx.x * blockDim.x + threadIdx.x;
    if (i >= n8) return;
    const float4* s4 = (const float4*)src;
    float4 a = s4[2 * (size_t)i];
    float4 b = s4[2 * (size_t)i + 1];
    f16x8 h;
    h[0] = (_Float16)a.x; h[1] = (_Float16)a.y; h[2] = (_Float16)a.z; h[3] = (_Float16)a.w;
    h[4] = (_Float16)b.x; h[5] = (_Float16)b.y; h[6] = (_Float16)b.z; h[7] = (_Float16)b.w;
    *(f16x8*)(dst + 8 * (size_t)i) = h;
}

// async global->LDS, 16B per lane, wave-uniform LDS base
__device__ __forceinline__ void async16(const char* g, _Float16* l) {
    __builtin_amdgcn_global_load_lds(
        (const __attribute__((address_space(1))) unsigned int*)(uintptr_t)g,
        (__attribute__((address_space(3))) unsigned int*)(uintptr_t)l,
        16, 0, 0);
}

// ================= 256x256 tile, BK=32, 4-buffer deep-pipelined GEMM =================
// A[M][K] f16, B=W[N][K] f16. Fused Ghost BN (128-row virtual batch == wr-half) + priors.
// LDS per buffer: A 256x32 f16 (16KB) + B 256x32 f16 (16KB); 4 buffers = 128KB.
// T2 swizzle: tile byte-addr ^= ((addr>>7)&3)<<4  (16B col-slot XOR row bits 1-2).
// LDS dest stays linear (global_load_lds); SOURCE is pre-permuted per lane; reads swizzled.

template<int WAITN, bool STAGE>
__device__ __forceinline__ void ktile(
    int kt, _Float16* As, _Float16* Bs,
    const char* a0, const char* a1, const char* b0, const char* b1,
    int wid, int aoff, int boff, f16x8 (&b)[4], f32x4 (&acc)[8][4])
{
    const char* ab = (const char*)As + ((kt & 3) << 14);
    const char* bb = (const char*)Bs + ((kt & 3) << 14);
    f16x8 a[4];

    // ---------- phase 0: quadrant m0-3 x n0-3 ----------
    #pragma unroll
    for (int m = 0; m < 4; ++m) a[m] = *(const f16x8*)(ab + aoff + m * 1024);
    #pragma unroll
    for (int n = 0; n < 4; ++n) b[n] = *(const f16x8*)(bb + boff + n * 1024);
    if (STAGE) {
        _Float16* d = As + ((kt + 3) & 3) * 8192 + wid * 512;
        async16(a0 + (size_t)(kt + 3) * 64, d);
        async16(a1 + (size_t)(kt + 3) * 64, d + 4096);
    }
    __builtin_amdgcn_s_barrier();
    asm volatile("s_waitcnt lgkmcnt(0)" ::: "memory");
    __builtin_amdgcn_sched_barrier(0);
    __builtin_amdgcn_s_setprio(1);
    #pragma unroll
    for (int m = 0; m < 4; ++m)
        #pragma unroll
        for (int n = 0; n < 4; ++n)
            acc[m][n] = __builtin_amdgcn_mfma_f32_16x16x32_f16(a[m], b[n], acc[m][n], 0, 0, 0);
    __builtin_amdgcn_s_setprio(0);
    __builtin_amdgcn_s_barrier();

    // ---------- phase 1: quadrant m4-7 x n0-3 (b[] reused) ----------
    #pragma unroll
    for (int m = 0; m < 4; ++m) a[m] = *(const f16x8*)(ab + aoff + (4 + m) * 1024);
    if (STAGE) {
        _Float16* d = Bs + ((kt + 3) & 3) * 8192 + wid * 512;
        async16(b0 + (size_t)(kt + 3) * 64, d);
        async16(b1 + (size_t)(kt + 3) * 64, d + 4096);
    }
    __builtin_amdgcn_s_barrier();
    asm volatile("s_waitcnt lgkmcnt(0)" ::: "memory");
    __builtin_amdgcn_sched_barrier(0);
    __builtin_amdgcn_s_setprio(1);
    #pragma unroll
    for (int m = 0; m < 4; ++m)
        #pragma unroll
        for (int n = 0; n < 4; ++n)
            acc[4 + m][n] = __builtin_amdgcn_mfma_f32_16x16x32_f16(a[m], b[n], acc[4 + m][n], 0, 0, 0);
    __builtin_amdgcn_s_setprio(0);
    if (WAITN == 8)      { asm volatile("s_waitcnt vmcnt(8)" ::: "memory"); }
    else if (WAITN == 4) { asm volatile("s_waitcnt vmcnt(4)" ::: "memory"); }
    else                 { asm volatile("s_waitcnt vmcnt(0)" ::: "memory"); }
    __builtin_amdgcn_sched_barrier(0);
    __builtin_amdgcn_s_barrier();
}

__global__ __launch_bounds__(512, 2)
void gemm_gbn_kernel(const _Float16* __restrict__ A,
                     const _Float16* __restrict__ Bw,
                     const float* __restrict__ priors,
                     const float* __restrict__ gamma,
                     const float* __restrict__ beta,
                     float* __restrict__ Z,
                     int M, int N, int K)
{
    __shared__ __align__(16) _Float16 As[4 * 8192];   // 64 KB
    __shared__ __align__(16) _Float16 Bs[4 * 8192];   // 64 KB

    const int tid  = threadIdx.x;
    const int lane = tid & 63;
    const int wid  = tid >> 6;     // 0..7
    const int wr   = wid >> 2;     // 0..1  (128-row half == one virtual batch)
    const int wc   = wid & 3;      // 0..3  (64-col slice)
    const int fr   = lane & 15;
    const int kg   = lane >> 4;

    // XCD-aware bijective swizzle (nwg = 512, divisible by 8)
    const int bid = blockIdx.x;
    const int swz = (bid & 7) * 64 + (bid >> 3);
    const int row0 = (swz >> 2) * 256;
    const int col0 = (swz & 3) * 256;

    // staging sources: thread t covers tile row t/4 (+128 for second issue).
    // T2 pre-permuted source col-slot: (lane&3) ^ ((lane>>3)&3)  (16B units)
    const int sperm = ((lane & 3) ^ ((lane >> 3) & 3)) * 16;
    const char* a0 = (const char*)A  + (size_t)(row0 + (tid >> 2)) * (size_t)K * 2 + sperm;
    const char* a1 = a0 + (size_t)128 * K * 2;
    const char* b0 = (const char*)Bw + (size_t)(col0 + (tid >> 2)) * (size_t)K * 2 + sperm;
    const char* b1 = b0 + (size_t)128 * K * 2;

    // LDS fragment byte offsets ([256][32] f16, 64B rows), T2-swizzled.
    // swz(addr) = addr ^ (((addr>>7)&3)<<4); invariant under +m*1024 / +n*1024.
    int aoff = (wr * 128 + fr) * 64 + kg * 16;
    aoff ^= ((aoff >> 7) & 3) << 4;
    int boff = (wc * 64 + fr) * 64 + kg * 16;
    boff ^= ((boff >> 7) & 3) << 4;

    f32x4 acc[8][4];
    #pragma unroll
    for (int m = 0; m < 8; ++m)
        #pragma unroll
        for (int n = 0; n < 4; ++n)
            acc[m][n] = (f32x4)0.0f;
    f16x8 bfrag[4];

    // prologue: stage K-tiles 0,1,2 (A then B each) -> buffers 0,1,2
    #pragma unroll
    for (int t = 0; t < 3; ++t) {
        _Float16* dA = As + t * 8192 + wid * 512;
        async16(a0 + (size_t)t * 64, dA);
        async16(a1 + (size_t)t * 64, dA + 4096);
        _Float16* dB = Bs + t * 8192 + wid * 512;
        async16(b0 + (size_t)t * 64, dB);
        async16(b1 + (size_t)t * 64, dB + 4096);
    }
    asm volatile("s_waitcnt vmcnt(8)" ::: "memory");   // tile 0 resident; tiles 1,2 in flight
    __builtin_amdgcn_sched_barrier(0);
    __builtin_amdgcn_s_barrier();

    const int nt = K >> 5;                 // 64 K-tiles
    for (int kt = 0; kt < nt - 3; ++kt)    // stages kt+3 (up to nt-1), waits vmcnt(8)
        ktile<8, true>(kt, As, Bs, a0, a1, b0, b1, wid, aoff, boff, bfrag, acc);
    ktile<4, false>(nt - 3, As, Bs, a0, a1, b0, b1, wid, aoff, boff, bfrag, acc);
    ktile<0, false>(nt - 2, As, Bs, a0, a1, b0, b1, wid, aoff, boff, bfrag, acc);
    ktile<0, false>(nt - 1, As, Bs, a0, a1, b0, b1, wid, aoff, boff, bfrag, acc);

    // ---- fused Ghost BatchNorm + priors epilogue (wave-local: wr half = one VBS) ----
    #pragma unroll
    for (int n = 0; n < 4; ++n) {
        float s1 = 0.f, s2 = 0.f;
        #pragma unroll
        for (int m = 0; m < 8; ++m)
            #pragma unroll
            for (int j = 0; j < 4; ++j) {
                float v = acc[m][n][j];
                s1 += v; s2 += v * v;
            }
        s1 += __shfl_xor(s1, 16); s2 += __shfl_xor(s2, 16);
        s1 += __shfl_xor(s1, 32); s2 += __shfl_xor(s2, 32);
        float mean = s1 * (1.f / 128.f);
        float var  = s2 * (1.f / 128.f) - mean * mean;
        float rstd = rsqrtf(var + BN_EPS);
        const int c = col0 + wc * 64 + n * 16 + fr;
        float g = gamma[c] * rstd;
        float b = beta[c] - mean * g;
        #pragma unroll
        for (int m = 0; m < 8; ++m)
            #pragma unroll
            for (int j = 0; j < 4; ++j) {
                int r = row0 + wr * 128 + m * 16 + kg * 4 + j;
                size_t off = (size_t)r * N + c;
                Z[off] = (acc[m][n][j] * g + b) * priors[off];
            }
    }
}

// ---------------- sparsemax: one wave per row of 1024, exact Michelot projection ----------------
__device__ __forceinline__ float waveSum(float v) {
    #pragma unroll
    for (int off = 32; off > 0; off >>= 1) v += __shfl_xor(v, off);
    return v;
}

__global__ __launch_bounds__(256)
void sparsemax_kernel(float* __restrict__ Z) {
    const int lane = threadIdx.x & 63;
    const int wid  = threadIdx.x >> 6;
    const size_t row = (size_t)blockIdx.x * 4 + wid;
    float4* zr4 = (float4*)(Z + row * 1024);

    float p[16];
    #pragma unroll
    for (int j = 0; j < 4; ++j) {
        float4 t = zr4[lane * 4 + j];
        p[4 * j + 0] = t.x; p[4 * j + 1] = t.y; p[4 * j + 2] = t.z; p[4 * j + 3] = t.w;
    }

    float s = 0.f;
    #pragma unroll
    for (int i = 0; i < 16; ++i) s += p[i];
    s = waveSum(s);

    float kc  = 1024.f;
    float tau = (s - 1.f) * (1.f / 1024.f);
    for (int it = 0; it < 64; ++it) {
        float s2 = 0.f, c2 = 0.f;
        #pragma unroll
        for (int i = 0; i < 16; ++i) {
            if (p[i] > tau) { s2 += p[i]; c2 += 1.f; }
        }
        s2 = waveSum(s2); c2 = waveSum(c2);
        if (c2 == kc) break;        // support stable -> tau exact
        kc = c2;
        tau = (s2 - 1.f) / c2;
    }

    #pragma unroll
    for (int j = 0; j < 4; ++j) {
        float4 o;
        o.x = fmaxf(p[4 * j + 0] - tau, 0.f);
        o.y = fmaxf(p[4 * j + 1] - tau, 0.f);
        o.z = fmaxf(p[4 * j + 2] - tau, 0.f);
        o.w = fmaxf(p[4 * j + 3] - tau, 0.f);
        zr4[lane * 4 + j] = o;
    }
}

extern "C" void kernel_launch(void* const* d_in, const int* in_sizes, int n_in,
                              void* d_out, int out_size, void* d_ws, size_t ws_size,
                              hipStream_t stream)
{
    const float* priors = (const float*)d_in[0];
    const float* feat   = (const float*)d_in[1];
    const float* W      = (const float*)d_in[2];
    const float* gamma  = (const float*)d_in[3];
    const float* beta   = (const float*)d_in[4];
    float* out = (float*)d_out;

    const int Nf = in_sizes[3];              // 1024
    const int Kf = in_sizes[2] / Nf;         // 2048
    const int Mr = in_sizes[1] / Kf;         // 32768

    _Float16* Ah = (_Float16*)d_ws;                                  // M*K*2 = 128 MB
    _Float16* Wh = (_Float16*)((char*)d_ws + (size_t)Mr * Kf * 2);   // N*K*2 =   4 MB

    {
        int n8 = Mr * (Kf / 8);
        cast_f32_f16<<<(n8 + 255) / 256, 256, 0, stream>>>(feat, Ah, n8);
    }
    {
        int n8 = Nf * (Kf / 8);
        cast_f32_f16<<<(n8 + 255) / 256, 256, 0, stream>>>(W, Wh, n8);
    }

    int nblk = (Mr / 256) * (Nf / 256);      // 512, divisible by 8
    gemm_gbn_kernel<<<nblk, 512, 0, stream>>>(Ah, Wh, priors, gamma, beta, out, Mr, Nf, Kf);

    sparsemax_kernel<<<Mr / 4, 256, 0, stream>>>(out);
}

// Round 4
// 336.603 us; speedup vs baseline: 1.2426x; 1.0028x over previous
//
#include <hip/hip_runtime.h>
#include <hip/hip_bf16.h>
#include <cstdint>

typedef __attribute__((ext_vector_type(4))) float f32x4;
typedef _Float16 f16x8 __attribute__((ext_vector_type(8)));

#define BN_EPS 1e-5f

// ---------------- fp32 -> fp16 cast (vectorized, 8 elems/thread) ----------------
__global__ __launch_bounds__(256)
void cast_f32_f16(const float* __restrict__ src, _Float16* __restrict__ dst, int n8) {
    int i = blockIdx.x * blockDim.x + threadIdx.x;
    if (i >= n8) return;
    const float4* s4 = (const float4*)src;
    float4 a = s4[2 * (size_t)i];
    float4 b = s4[2 * (size_t)i + 1];
    f16x8 h;
    h[0] = (_Float16)a.x; h[1] = (_Float16)a.y; h[2] = (_Float16)a.z; h[3] = (_Float16)a.w;
    h[4] = (_Float16)b.x; h[5] = (_Float16)b.y; h[6] = (_Float16)b.z; h[7] = (_Float16)b.w;
    *(f16x8*)(dst + 8 * (size_t)i) = h;
}

// async global->LDS, 16B per lane, wave-uniform LDS base
__device__ __forceinline__ void async16(const char* g, _Float16* l) {
    __builtin_amdgcn_global_load_lds(
        (const __attribute__((address_space(1))) unsigned int*)(uintptr_t)g,
        (__attribute__((address_space(3))) unsigned int*)(uintptr_t)l,
        16, 0, 0);
}

// ================= 256x256 tile, BK=32, 4-buffer deep-pipelined GEMM =================
// One phase per K-tile: {stage kt+3 -> 12 ds_read (b first) -> 32 MFMA -> vmcnt(8) -> barrier}.
// Compiler-managed incremental lgkmcnt between ds_read and MFMA (no manual drain, no
// sched_barrier) so address-VALU and waits co-schedule under the MFMA cluster.
// Hazards: reads of slot s drained before the closing barrier of the K-tile that read it;
// stage into slot (kt+3)&3 == (kt-1)&3 only issues after that barrier. vmcnt(8) keeps
// exactly 2 K-tiles of staging in flight; tile kt+1 is resident at kt's closing barrier.

template<int WAITN, bool STAGE>
__device__ __forceinline__ void ktile(
    int kt, _Float16* As, _Float16* Bs,
    const char* a0, const char* a1, const char* b0, const char* b1,
    int wid, int aoff, int boff, f32x4 (&acc)[8][4])
{
    if (STAGE) {
        _Float16* dA = As + ((kt + 3) & 3) * 8192 + wid * 512;
        async16(a0 + (size_t)(kt + 3) * 64, dA);
        async16(a1 + (size_t)(kt + 3) * 64, dA + 4096);
        _Float16* dB = Bs + ((kt + 3) & 3) * 8192 + wid * 512;
        async16(b0 + (size_t)(kt + 3) * 64, dB);
        async16(b1 + (size_t)(kt + 3) * 64, dB + 4096);
    }
    const char* ab = (const char*)As + ((kt & 3) << 14);
    const char* bb = (const char*)Bs + ((kt & 3) << 14);
    f16x8 a[8], b[4];
    #pragma unroll
    for (int n = 0; n < 4; ++n) b[n] = *(const f16x8*)(bb + boff + n * 1024);
    #pragma unroll
    for (int m = 0; m < 8; ++m) a[m] = *(const f16x8*)(ab + aoff + m * 1024);
    __builtin_amdgcn_s_setprio(1);
    #pragma unroll
    for (int m = 0; m < 8; ++m)
        #pragma unroll
        for (int n = 0; n < 4; ++n)
            acc[m][n] = __builtin_amdgcn_mfma_f32_16x16x32_f16(a[m], b[n], acc[m][n], 0, 0, 0);
    __builtin_amdgcn_s_setprio(0);
    if (WAITN == 8)      { asm volatile("s_waitcnt vmcnt(8)" ::: "memory"); }
    else if (WAITN == 4) { asm volatile("s_waitcnt vmcnt(4)" ::: "memory"); }
    else                 { asm volatile("s_waitcnt vmcnt(0)" ::: "memory"); }
    __builtin_amdgcn_s_barrier();
}

__global__ __launch_bounds__(512, 2)
void gemm_gbn_kernel(const _Float16* __restrict__ A,
                     const _Float16* __restrict__ Bw,
                     const float* __restrict__ priors,
                     const float* __restrict__ gamma,
                     const float* __restrict__ beta,
                     float* __restrict__ Z,
                     int M, int N, int K)
{
    __shared__ __align__(16) _Float16 As[4 * 8192];   // 64 KB
    __shared__ __align__(16) _Float16 Bs[4 * 8192];   // 64 KB

    const int tid  = threadIdx.x;
    const int lane = tid & 63;
    const int wid  = tid >> 6;     // 0..7
    const int wr   = wid >> 2;     // 0..1  (128-row half == one virtual batch)
    const int wc   = wid & 3;      // 0..3  (64-col slice)
    const int fr   = lane & 15;
    const int kg   = lane >> 4;

    // XCD-aware bijective swizzle (nwg = 512, divisible by 8)
    const int bid = blockIdx.x;
    const int swz = (bid & 7) * 64 + (bid >> 3);
    const int row0 = (swz >> 2) * 256;
    const int col0 = (swz & 3) * 256;

    // staging sources: thread t covers tile row t/4 (+128 for second issue).
    // T2 pre-permuted source col-slot: (lane&3) ^ ((lane>>3)&3)  (16B units)
    const int sperm = ((lane & 3) ^ ((lane >> 3) & 3)) * 16;
    const char* a0 = (const char*)A  + (size_t)(row0 + (tid >> 2)) * (size_t)K * 2 + sperm;
    const char* a1 = a0 + (size_t)128 * K * 2;
    const char* b0 = (const char*)Bw + (size_t)(col0 + (tid >> 2)) * (size_t)K * 2 + sperm;
    const char* b1 = b0 + (size_t)128 * K * 2;

    // LDS fragment byte offsets ([256][32] f16, 64B rows), T2-swizzled.
    // swz(addr) = addr ^ (((addr>>7)&3)<<4); invariant under +m*1024 / +n*1024.
    int aoff = (wr * 128 + fr) * 64 + kg * 16;
    aoff ^= ((aoff >> 7) & 3) << 4;
    int boff = (wc * 64 + fr) * 64 + kg * 16;
    boff ^= ((boff >> 7) & 3) << 4;

    f32x4 acc[8][4];
    #pragma unroll
    for (int m = 0; m < 8; ++m)
        #pragma unroll
        for (int n = 0; n < 4; ++n)
            acc[m][n] = (f32x4)0.0f;

    // prologue: stage K-tiles 0,1,2 -> buffers 0,1,2
    #pragma unroll
    for (int t = 0; t < 3; ++t) {
        _Float16* dA = As + t * 8192 + wid * 512;
        async16(a0 + (size_t)t * 64, dA);
        async16(a1 + (size_t)t * 64, dA + 4096);
        _Float16* dB = Bs + t * 8192 + wid * 512;
        async16(b0 + (size_t)t * 64, dB);
        async16(b1 + (size_t)t * 64, dB + 4096);
    }
    asm volatile("s_waitcnt vmcnt(8)" ::: "memory");   // tile 0 resident; tiles 1,2 in flight
    __builtin_amdgcn_s_barrier();

    const int nt = K >> 5;                 // 64 K-tiles
    for (int kt = 0; kt < nt - 3; ++kt)    // stages kt+3 (up to nt-1), waits vmcnt(8)
        ktile<8, true>(kt, As, Bs, a0, a1, b0, b1, wid, aoff, boff, acc);
    ktile<4, false>(nt - 3, As, Bs, a0, a1, b0, b1, wid, aoff, boff, acc);
    ktile<0, false>(nt - 2, As, Bs, a0, a1, b0, b1, wid, aoff, boff, acc);
    ktile<0, false>(nt - 1, As, Bs, a0, a1, b0, b1, wid, aoff, boff, acc);

    // ---- fused Ghost BatchNorm + priors epilogue (wave-local: wr half = one VBS) ----
    #pragma unroll
    for (int n = 0; n < 4; ++n) {
        float s1 = 0.f, s2 = 0.f;
        #pragma unroll
        for (int m = 0; m < 8; ++m)
            #pragma unroll
            for (int j = 0; j < 4; ++j) {
                float v = acc[m][n][j];
                s1 += v; s2 += v * v;
            }
        s1 += __shfl_xor(s1, 16); s2 += __shfl_xor(s2, 16);
        s1 += __shfl_xor(s1, 32); s2 += __shfl_xor(s2, 32);
        float mean = s1 * (1.f / 128.f);
        float var  = s2 * (1.f / 128.f) - mean * mean;
        float rstd = rsqrtf(var + BN_EPS);
        const int c = col0 + wc * 64 + n * 16 + fr;
        float g = gamma[c] * rstd;
        float b = beta[c] - mean * g;
        #pragma unroll
        for (int m = 0; m < 8; ++m)
            #pragma unroll
            for (int j = 0; j < 4; ++j) {
                int r = row0 + wr * 128 + m * 16 + kg * 4 + j;
                size_t off = (size_t)r * N + c;
                Z[off] = (acc[m][n][j] * g + b) * priors[off];
            }
    }
}

// ---------------- sparsemax: one wave per row of 1024, exact Michelot projection ----------------
__device__ __forceinline__ float waveSum(float v) {
    #pragma unroll
    for (int off = 32; off > 0; off >>= 1) v += __shfl_xor(v, off);
    return v;
}

__global__ __launch_bounds__(256)
void sparsemax_kernel(float* __restrict__ Z) {
    const int lane = threadIdx.x & 63;
    const int wid  = threadIdx.x >> 6;
    const size_t row = (size_t)blockIdx.x * 4 + wid;
    float4* zr4 = (float4*)(Z + row * 1024);

    float p[16];
    #pragma unroll
    for (int j = 0; j < 4; ++j) {
        float4 t = zr4[lane * 4 + j];
        p[4 * j + 0] = t.x; p[4 * j + 1] = t.y; p[4 * j + 2] = t.z; p[4 * j + 3] = t.w;
    }

    float s = 0.f;
    #pragma unroll
    for (int i = 0; i < 16; ++i) s += p[i];
    s = waveSum(s);

    float kc  = 1024.f;
    float tau = (s - 1.f) * (1.f / 1024.f);
    for (int it = 0; it < 64; ++it) {
        float s2 = 0.f, c2 = 0.f;
        #pragma unroll
        for (int i = 0; i < 16; ++i) {
            if (p[i] > tau) { s2 += p[i]; c2 += 1.f; }
        }
        s2 = waveSum(s2); c2 = waveSum(c2);
        if (c2 == kc) break;        // support stable -> tau exact
        kc = c2;
        tau = (s2 - 1.f) / c2;
    }

    #pragma unroll
    for (int j = 0; j < 4; ++j) {
        float4 o;
        o.x = fmaxf(p[4 * j + 0] - tau, 0.f);
        o.y = fmaxf(p[4 * j + 1] - tau, 0.f);
        o.z = fmaxf(p[4 * j + 2] - tau, 0.f);
        o.w = fmaxf(p[4 * j + 3] - tau, 0.f);
        zr4[lane * 4 + j] = o;
    }
}

extern "C" void kernel_launch(void* const* d_in, const int* in_sizes, int n_in,
                              void* d_out, int out_size, void* d_ws, size_t ws_size,
                              hipStream_t stream)
{
    const float* priors = (const float*)d_in[0];
    const float* feat   = (const float*)d_in[1];
    const float* W      = (const float*)d_in[2];
    const float* gamma  = (const float*)d_in[3];
    const float* beta   = (const float*)d_in[4];
    float* out = (float*)d_out;

    const int Nf = in_sizes[3];              // 1024
    const int Kf = in_sizes[2] / Nf;         // 2048
    const int Mr = in_sizes[1] / Kf;         // 32768

    _Float16* Ah = (_Float16*)d_ws;                                  // M*K*2 = 128 MB
    _Float16* Wh = (_Float16*)((char*)d_ws + (size_t)Mr * Kf * 2);   // N*K*2 =   4 MB

    {
        int n8 = Mr * (Kf / 8);
        cast_f32_f16<<<(n8 + 255) / 256, 256, 0, stream>>>(feat, Ah, n8);
    }
    {
        int n8 = Nf * (Kf / 8);
        cast_f32_f16<<<(n8 + 255) / 256, 256, 0, stream>>>(W, Wh, n8);
    }

    int nblk = (Mr / 256) * (Nf / 256);      // 512, divisible by 8
    gemm_gbn_kernel<<<nblk, 512, 0, stream>>>(Ah, Wh, priors, gamma, beta, out, Mr, Nf, Kf);

    sparsemax_kernel<<<Mr / 4, 256, 0, stream>>>(out);
}